// Round 1
// baseline (10.155 us; speedup 1.0000x reference)
//
#include <hip/hip_runtime.h>
#include <hip/hip_bf16.h>

// out[d*L + l] = embedding[(L-1)*D + d]   (fp32)
// Each thread writes one float4 (4 consecutive l's, same d since L % 4 == 0).
__global__ void relposemb_diag_kernel(const float* __restrict__ emb,
                                      float* __restrict__ out,
                                      int L, int D, int total4) {
    int tid = blockIdx.x * blockDim.x + threadIdx.x;  // float4 index
    if (tid >= total4) return;
    int elem = tid << 2;          // first element index
    int d = elem / L;             // row of output (L is multiple of 4)
    float v = emb[(L - 1) * D + d];
    float4 o = make_float4(v, v, v, v);
    reinterpret_cast<float4*>(out)[tid] = o;
}

// Fallback for L not divisible by 4 (not expected here, but keep it correct).
__global__ void relposemb_diag_scalar_kernel(const float* __restrict__ emb,
                                             float* __restrict__ out,
                                             int L, int D, int total) {
    int tid = blockIdx.x * blockDim.x + threadIdx.x;
    if (tid >= total) return;
    int d = tid / L;
    out[tid] = emb[(L - 1) * D + d];
}

extern "C" void kernel_launch(void* const* d_in, const int* in_sizes, int n_in,
                              void* d_out, int out_size, void* d_ws, size_t ws_size,
                              hipStream_t stream) {
    const float* emb = (const float*)d_in[0];
    float* out = (float*)d_out;

    // in_sizes[0] = (2L-1)*D, out_size = D*L  =>  D = 2*out_size - in_sizes[0]
    int D = 2 * out_size - in_sizes[0];
    int L = out_size / D;

    if ((L & 3) == 0) {
        int total4 = out_size >> 2;
        int block = 256;
        int grid = (total4 + block - 1) / block;
        relposemb_diag_kernel<<<grid, block, 0, stream>>>(emb, out, L, D, total4);
    } else {
        int block = 256;
        int grid = (out_size + block - 1) / block;
        relposemb_diag_scalar_kernel<<<grid, block, 0, stream>>>(emb, out, L, D, out_size);
    }
}